// Round 2
// baseline (289.098 us; speedup 1.0000x reference)
//
#include <hip/hip_runtime.h>
#include <stdint.h>

// Problem: B=131072 rows, K=IN=256, N=OUT=256.
// temp = act @ weight.T (exact int32 values, |t| < 2^24)
// r = max|temp|; bw = ceil(log2(max(r,1))) (0 if r==0); shift = bw-7
// if shift>0: round_shift(temp, shift) clipped to [-127,127] else temp -> int8
// exp_out = exp_in + weight_exp + (shift>0 ? shift : 0) -> int16
// Harness reads d_out as INT32: [B*N quantized values, 1 exp scalar].

#define M_ROWS 131072
#define NK 256      // N == K == 256
#define BM 64
#define BK 64
#define BKP 72      // padded LDS row stride in bf16 elems (144 B, 16B-aligned)

typedef __attribute__((ext_vector_type(8))) short bf16x8;
typedef __attribute__((ext_vector_type(4))) float f32x4;
typedef __attribute__((ext_vector_type(4))) unsigned int u32x4;

__device__ __forceinline__ uint32_t pack_bf16(float a, float b) {
  // exact for integer-valued floats |v| <= 255 (low 16 fp32 bits are zero)
  return (__float_as_uint(a) >> 16) | (__float_as_uint(b) & 0xFFFF0000u);
}

__device__ __forceinline__ void pack8(const float4 f0, const float4 f1, uint32_t pk[4]) {
  pk[0] = pack_bf16(f0.x, f0.y);
  pk[1] = pack_bf16(f0.z, f0.w);
  pk[2] = pack_bf16(f1.x, f1.y);
  pk[3] = pack_bf16(f1.z, f1.w);
}

// Pass 1: GEMM -> int32 temp (into d_out) + global abs-max (into d_ws[0]).
// Block: 256 threads (4 waves). Block tile: 64 rows x 256 cols (full N).
// Wave w computes rows 0..63, cols w*64..w*64+63 as 4x4 mfma 16x16x32 tiles.
__global__ __launch_bounds__(256, 3) void gemm_pass1(
    const float* __restrict__ act,   // [M_ROWS, 256] int-valued fp32
    const float* __restrict__ wgt,   // [256, 256]   int-valued fp32
    int* __restrict__ temp,          // [M_ROWS, 256] output (int32)
    int* __restrict__ gmax)          // [1] global abs-max (pre-zeroed)
{
  __shared__ __align__(16) short As[BM * BKP];   //  9216 B
  __shared__ __align__(16) short Bs[NK * BKP];   // 36864 B
  __shared__ int smax;

  const int tid = threadIdx.x;
  if (tid == 0) smax = 0;

  const int bm   = blockIdx.x * BM;
  const int lane = tid & 63;
  const int wave = tid >> 6;     // 0..3
  const int lm   = lane & 15;    // mfma row/col within 16
  const int lk   = lane >> 4;    // 0..3 quad
  const int wn   = wave * 64;    // wave's N offset within the 256-wide tile

  f32x4 acc[4][4] = {};          // zero-init accumulators

  for (int kt = 0; kt < NK; kt += BK) {
    uint32_t apk[2][4];
    uint32_t bpk[8][4];
    // A tile: 64 rows x 64 k = 4096 elems; chunk = 8 consecutive k.
#pragma unroll
    for (int j = 0; j < 2; ++j) {
      const int c = tid + (j << 8);
      const float* p = act + (size_t)(bm + (c >> 3)) * NK + kt + (c & 7) * 8;
      const float4 f0 = ((const float4*)p)[0];
      const float4 f1 = ((const float4*)p)[1];
      pack8(f0, f1, apk[j]);
    }
    // B tile: 256 rows x 64 k = 16384 elems (weight is [N,K] row-major: B^T form)
#pragma unroll
    for (int j = 0; j < 8; ++j) {
      const int c = tid + (j << 8);
      const float* p = wgt + (size_t)(c >> 3) * NK + kt + (c & 7) * 8;
      const float4 f0 = ((const float4*)p)[0];
      const float4 f1 = ((const float4*)p)[1];
      pack8(f0, f1, bpk[j]);
    }

    __syncthreads();   // previous iteration's LDS reads complete
#pragma unroll
    for (int j = 0; j < 2; ++j) {
      const int c = tid + (j << 8);
      *(u32x4*)&As[(c >> 3) * BKP + (c & 7) * 8] = *(const u32x4*)apk[j];
    }
#pragma unroll
    for (int j = 0; j < 8; ++j) {
      const int c = tid + (j << 8);
      *(u32x4*)&Bs[(c >> 3) * BKP + (c & 7) * 8] = *(const u32x4*)bpk[j];
    }
    __syncthreads();

#pragma unroll
    for (int kk = 0; kk < BK; kk += 32) {
      bf16x8 af[4], bfr[4];
#pragma unroll
      for (int mi = 0; mi < 4; ++mi)
        af[mi] = *(const bf16x8*)&As[(mi * 16 + lm) * BKP + kk + lk * 8];
#pragma unroll
      for (int ni = 0; ni < 4; ++ni)
        bfr[ni] = *(const bf16x8*)&Bs[(wn + ni * 16 + lm) * BKP + kk + lk * 8];
#pragma unroll
      for (int mi = 0; mi < 4; ++mi)
#pragma unroll
        for (int ni = 0; ni < 4; ++ni)
          acc[mi][ni] = __builtin_amdgcn_mfma_f32_16x16x32_bf16(
              af[mi], bfr[ni], acc[mi][ni], 0, 0, 0);
    }
  }

  // Epilogue: C/D layout col = lane&15, row = (lane>>4)*4 + reg  [m89]
  int imax = 0;
#pragma unroll
  for (int mi = 0; mi < 4; ++mi)
#pragma unroll
    for (int ni = 0; ni < 4; ++ni)
#pragma unroll
      for (int r = 0; r < 4; ++r) {
        const float v = acc[mi][ni][r];
        const int iv = (int)v;                  // exact integer
        const int m = bm + mi * 16 + lk * 4 + r;
        const int n = wn + ni * 16 + lm;
        temp[(size_t)m * NK + n] = iv;
        const int a = iv < 0 ? -iv : iv;
        imax = a > imax ? a : imax;
      }
  atomicMax(&smax, imax);
  __syncthreads();
  if (tid == 0) atomicMax(gmax, smax);
}

// Pass 2: in-place quantize int32 temp -> int32(int8 value); write exp scalar.
__global__ void quant_pass2(int* __restrict__ temp,
                            const int* __restrict__ gmax,
                            const int* __restrict__ exp_in,
                            const int* __restrict__ wexp)
{
  const int r = *gmax;
  const int bw = (r <= 1) ? 0 : (32 - __clz(r - 1));   // ceil(log2(r)), r>0
  const int shift = bw - 7;
  const bool pos = shift > 0;
  const int s = shift < 1 ? 1 : shift;

  const int total4 = (M_ROWS * NK) / 4;   // 8388608
  int4* p = (int4*)temp;
  const int idx = blockIdx.x * blockDim.x + threadIdx.x;
  const int stride = gridDim.x * blockDim.x;

  for (int i = idx; i < total4; i += stride) {
    const int4 t = p[i];
    int4 o;
#pragma unroll
    for (int j = 0; j < 4; ++j) {
      const int ti = ((const int*)&t)[j];
      int q;
      if (pos) {
        const int rt = ti >> s;                       // floor(t / 2^s)
        const int dec = (ti - (rt << s)) >> (s - 1);  // floor(rem / 2^(s-1)) in {0,1}
        q = rt + dec;
        q = q > 127 ? 127 : (q < -127 ? -127 : q);
      } else {
        q = (int)(signed char)(ti & 0xFF);            // int8 cast w/ wrap
      }
      ((int*)&o)[j] = q;
    }
    p[i] = o;
  }

  if (idx == 0) {
    const int e = exp_in[0] + wexp[0] + (pos ? shift : 0);
    temp[(size_t)M_ROWS * NK] = (int)(short)e;        // int16 semantics, stored int32
  }
}

extern "C" void kernel_launch(void* const* d_in, const int* in_sizes, int n_in,
                              void* d_out, int out_size, void* d_ws, size_t ws_size,
                              hipStream_t stream) {
  const float* act   = (const float*)d_in[0];
  const int* exp_in  = (const int*)d_in[1];
  const float* wgt   = (const float*)d_in[2];
  const int* wexp    = (const int*)d_in[3];
  int* gmax = (int*)d_ws;

  hipMemsetAsync(d_ws, 0, sizeof(int), stream);   // stream-ordered, capture-safe
  gemm_pass1<<<dim3(M_ROWS / BM), dim3(256), 0, stream>>>(act, wgt, (int*)d_out, gmax);
  quant_pass2<<<dim3(4096), dim3(256), 0, stream>>>((int*)d_out, gmax, exp_in, wexp);
}